// Round 11
// baseline (581.377 us; speedup 1.0000x reference)
//
#include <hip/hip_runtime.h>
#include <stdint.h>

#define B_ 2
#define S_ 1024
#define HID 2048
#define NK 16
#define NV 32
#define DK_ 128
#define DV_ 128
#define QKVZ_N 12288
#define TOK (B_*S_)

typedef unsigned short u16;
typedef __bf16 bf16x8 __attribute__((ext_vector_type(8)));
typedef float f32x4 __attribute__((ext_vector_type(4)));
typedef unsigned short u16x8 __attribute__((ext_vector_type(8)));
typedef unsigned short u16x4 __attribute__((ext_vector_type(4)));

__device__ __forceinline__ float bf2f(u16 u) {
    return __builtin_bit_cast(float, (unsigned)u << 16);
}
__device__ __forceinline__ u16 f2bf(float f) {
    unsigned u = __builtin_bit_cast(unsigned, f);
    u += 0x7fff + ((u >> 16) & 1);
    return (u16)(u >> 16);
}

// async global -> LDS. LDS dest: wave-uniform base + lane*16; global src per-lane.
__device__ __forceinline__ void gl16(const void* g, void* l) {
    __builtin_amdgcn_global_load_lds((const __attribute__((address_space(1))) uint32_t*)g,
                                     (__attribute__((address_space(3))) uint32_t*)l, 16, 0, 0);
}

// Swizzled LDS fragment read (XOR row&7 on 16B granules).
__device__ __forceinline__ bf16x8 fragld(const u16* base, int row, int col, int rowhw) {
    int idx = row * rowhw + ((((col >> 3) ^ (row & 7))) << 3);
    return __builtin_bit_cast(bf16x8, *(const u16x8*)(base + idx));
}
__device__ __forceinline__ int swzidx(int row, int col, int rowhw) {
    return row * rowhw + (((col >> 3) ^ (row & 7)) << 3) + (col & 7);
}

// ---------------- fp32 -> bf16 elementwise ----------------
__global__ void k_cvt_bf16(const float* __restrict__ in, u16* __restrict__ out, int n) {
    int i = (blockIdx.x * blockDim.x + threadIdx.x) * 4;
    if (i >= n) return;
    float4 v = *(const float4*)(in + i);
    u16x4 o = { f2bf(v.x), f2bf(v.y), f2bf(v.z), f2bf(v.w) };
    *(u16x4*)(out + i) = o;
}

// ---------------- fp32 (R,C) -> bf16 (C,R) tiled transpose ----------------
__global__ void k_transpose(const float* __restrict__ in, u16* __restrict__ out, int R, int C) {
    __shared__ float tile[32][33];
    int c0 = blockIdx.x * 32, r0 = blockIdx.y * 32;
    int tx = threadIdx.x, ty = threadIdx.y;  // (32,8)
#pragma unroll
    for (int i = 0; i < 4; i++)
        tile[ty + i * 8][tx] = in[(size_t)(r0 + ty + i * 8) * C + c0 + tx];
    __syncthreads();
#pragma unroll
    for (int i = 0; i < 4; i++)
        out[(size_t)(c0 + ty + i * 8) * R + r0 + tx] = f2bf(tile[tx][ty + i * 8]);
}

// ---------------- 256x128 bf16 GEMM, 4 waves, wave tile 64x128 ----------------
// Counted-vmcnt 3-buffer pipeline. Boundary is now race-free:
//   s_waitcnt vmcnt(6) lgkmcnt(0)  -> my tile-t loads landed AND my ds_reads executed
//   s_barrier                      -> published to all waves
//   sched_barrier(0)               -> stage's gl16s cannot hoist above the barrier
// (R10's boundary lacked lgkmcnt(0): a lagging wave could arrive at the barrier with
//  tile-(t-1) ds_reads still in flight while another wave's stage(t+2) overwrote
//  buf (t-1)%3 -> replay-timing-dependent corruption.)
__global__ __launch_bounds__(256) void k_gemm256(const u16* __restrict__ A, const u16* __restrict__ Bt,
                                                 u16* __restrict__ C, int K, int ldc) {
    __shared__ u16 lds[3 * 12288];  // buf b: A (8192 u16) at b*12288, B (4096 u16) at +8192
    int tid = threadIdx.x, wid = tid >> 6, lane = tid & 63;
    int l15 = lane & 15, lg = lane >> 4;
    int L = blockIdx.x;
    int xcd = L & 7, j = L >> 3;
    int bn = xcd * 12 + (j >> 3);
    int bm = j & 7;
    const u16* Ag = A + (size_t)bm * 256 * K;
    const u16* Bg = Bt + (size_t)bn * 128 * K;

    // per-row granule rotation: lds granule p holds global granule (p + 4 - (row>>1)) & 3.
    auto stage = [&](int t, int b) {
        u16* basebuf = &lds[b * 12288];
        int kcol = t * 32;
#pragma unroll
        for (int jj = 0; jj < 4; jj++) {
            int chunk = wid * 4 + jj;      // 16 A chunks (16 rows x 32 cols each)
            int row = chunk * 16 + (lane >> 2);
            int gg = ((lane & 3) + 4 - ((row >> 1) & 3)) & 3;
            gl16(Ag + (size_t)row * K + kcol + gg * 8, (char*)basebuf + chunk * 1024);
        }
#pragma unroll
        for (int jj = 0; jj < 2; jj++) {
            int chunk = wid * 2 + jj;      // 8 B chunks
            int row = chunk * 16 + (lane >> 2);
            int gg = ((lane & 3) + 4 - ((row >> 1) & 3)) & 3;
            gl16(Bg + (size_t)row * K + kcol + gg * 8, (char*)(basebuf + 8192) + chunk * 1024);
        }
    };
    auto ldfA = [&](int bsel, int row) -> bf16x8 {
        const u16* p = &lds[bsel * 12288];
        int g = (lg + (row >> 1)) & 3;
        return __builtin_bit_cast(bf16x8, *(const u16x8*)(p + row * 32 + g * 8));
    };
    auto ldfB = [&](int bsel, int row) -> bf16x8 {
        const u16* p = &lds[bsel * 12288 + 8192];
        int g = (lg + (row >> 1)) & 3;
        return __builtin_bit_cast(bf16x8, *(const u16x8*)(p + row * 32 + g * 8));
    };

    f32x4 acc[4][8] = {};
    int NT = K >> 5;
    stage(0, 0);
    stage(1, 1);
    for (int t = 0; t < NT; ++t) {
        if (t < NT - 1) asm volatile("s_waitcnt vmcnt(6) lgkmcnt(0)" ::: "memory");
        else            asm volatile("s_waitcnt vmcnt(0) lgkmcnt(0)" ::: "memory");
        __builtin_amdgcn_s_barrier();
        __builtin_amdgcn_sched_barrier(0);
        if (t + 2 < NT) stage(t + 2, (t + 2) % 3);
        int bsel = t % 3;
        bf16x8 bfr[8];
#pragma unroll
        for (int ni = 0; ni < 8; ni++) bfr[ni] = ldfB(bsel, ni * 16 + l15);
        __builtin_amdgcn_s_setprio(1);
#pragma unroll
        for (int mi = 0; mi < 4; mi++) {
            bf16x8 af = ldfA(bsel, wid * 64 + mi * 16 + l15);
#pragma unroll
            for (int ni = 0; ni < 8; ni++)
                acc[mi][ni] = __builtin_amdgcn_mfma_f32_16x16x32_bf16(af, bfr[ni], acc[mi][ni], 0, 0, 0);
        }
        __builtin_amdgcn_s_setprio(0);
    }
#pragma unroll
    for (int mi = 0; mi < 4; mi++) {
        int gr0 = bm * 256 + wid * 64 + mi * 16 + lg * 4;
#pragma unroll
        for (int ni = 0; ni < 8; ni++) {
            int gc = bn * 128 + ni * 16 + l15;
#pragma unroll
            for (int r = 0; r < 4; r++)
                C[(size_t)(gr0 + r) * ldc + gc] = f2bf(acc[mi][ni][r]);
        }
    }
}

// ---------------- bf16 GEMM: 128x128 (output projection) ----------------
template <int OUT_BF16>
__global__ __launch_bounds__(256) void k_gemm(const u16* __restrict__ A, const u16* __restrict__ Bt,
                                              void* __restrict__ Cv, int K, int ldc) {
    __shared__ u16 As[128 * 32];
    __shared__ u16 Bs[128 * 32];
    int tid = threadIdx.x;
    int bm = blockIdx.y, bn = blockIdx.x;
    int wid = tid >> 6, lane = tid & 63;
    int wm = wid >> 1, wn = wid & 1;
    int l15 = lane & 15, lg = lane >> 4;
    const u16* src0 = (wid >> 1) ? (Bt + (size_t)bn * 128 * K) : (A + (size_t)bm * 128 * K);
    u16* ldsb = (wid >> 1) ? Bs : As;
    int cbase = (wid & 1) * 4;
    int lrow = lane >> 2, lcol = (lane & 3) * 8;
    f32x4 acc[4][4] = {};
    for (int k0 = 0; k0 < K; k0 += 32) {
        if (k0) __syncthreads();
#pragma unroll
        for (int c = 0; c < 4; c++) {
            int ch = cbase + c;
            gl16(src0 + (size_t)(16 * ch + lrow) * K + k0 + lcol, (char*)ldsb + ch * 1024);
        }
        __syncthreads();
        bf16x8 af[4], bf[4];
#pragma unroll
        for (int mi = 0; mi < 4; mi++)
            af[mi] = __builtin_bit_cast(bf16x8, *(const u16x8*)&As[(wm * 64 + mi * 16 + l15) * 32 + lg * 8]);
#pragma unroll
        for (int ni = 0; ni < 4; ni++)
            bf[ni] = __builtin_bit_cast(bf16x8, *(const u16x8*)&Bs[(wn * 64 + ni * 16 + l15) * 32 + lg * 8]);
#pragma unroll
        for (int mi = 0; mi < 4; mi++)
#pragma unroll
            for (int ni = 0; ni < 4; ni++)
                acc[mi][ni] = __builtin_amdgcn_mfma_f32_16x16x32_bf16(af[mi], bf[ni], acc[mi][ni], 0, 0, 0);
    }
#pragma unroll
    for (int mi = 0; mi < 4; mi++) {
        int gr0 = bm * 128 + wm * 64 + mi * 16 + lg * 4;
#pragma unroll
        for (int ni = 0; ni < 4; ni++) {
            int gc = bn * 128 + wn * 64 + ni * 16 + l15;
#pragma unroll
            for (int r = 0; r < 4; r++) {
                if (OUT_BF16)
                    ((u16*)Cv)[(size_t)(gr0 + r) * ldc + gc] = f2bf(acc[mi][ni][r]);
                else
                    ((float*)Cv)[(size_t)(gr0 + r) * ldc + gc] = acc[mi][ni][r];
            }
        }
    }
}

// ---------------- ba = hidden @ W_ba (fp32, N=64) ----------------
__global__ void k_ba(const float* __restrict__ hid, const float* __restrict__ Wba, float* __restrict__ ba) {
    int token = blockIdx.x;
    int c = threadIdx.x;
    const float* h = hid + (size_t)token * HID;
    const float* w = Wba + c;
    float acc = 0.f;
    for (int k = 0; k < HID; k += 4) {
        float4 hv = *(const float4*)(h + k);
        acc += hv.x * w[(size_t)k * 64] + hv.y * w[(size_t)(k + 1) * 64] +
               hv.z * w[(size_t)(k + 2) * 64] + hv.w * w[(size_t)(k + 3) * 64];
    }
    ba[(size_t)token * 64 + c] = acc;
}

// ---------------- causal depthwise conv4 + silu + l2norm -> bf16 + {g_raw,beta} ----------------
__global__ __launch_bounds__(256) void k_conv(const u16* __restrict__ qkvz, const float* __restrict__ ba,
                                              const float* __restrict__ cw, const float* __restrict__ A_log,
                                              const float* __restrict__ dt_bias, u16* __restrict__ qsb,
                                              u16* __restrict__ ksb, u16* __restrict__ vsb,
                                              float2* __restrict__ gb2) {
    __shared__ float sm[4096];
    int token = blockIdx.x;
    int b = token >> 10;
    int t = token & (S_ - 1);
    int tid = threadIdx.x;
    const u16* row3 = qkvz + (size_t)token * QKVZ_N;
#pragma unroll
    for (int i = 0; i < 32; i++) {
        int c = tid + i * 256;
        int col;
        if (c < 2048) col = (c >> 7) * 768 + (c & 127);
        else if (c < 4096) col = ((c - 2048) >> 7) * 768 + 128 + (c & 127);
        else {
            int cc = c - 4096;
            col = (cc >> 8) * 768 + 256 + ((cc >> 7) & 1) * 128 + (cc & 127);
        }
        float4 w = *(const float4*)(cw + c * 4);
        float x3 = bf2f(row3[col]);
        float x2 = (t >= 1) ? bf2f(row3[col - QKVZ_N]) : 0.f;
        float x1 = (t >= 2) ? bf2f(row3[col - 2 * QKVZ_N]) : 0.f;
        float x0 = (t >= 3) ? bf2f(row3[col - 3 * QKVZ_N]) : 0.f;
        float s = w.x * x0 + w.y * x1 + w.z * x2 + w.w * x3;
        s = s / (1.f + __expf(-s));  // silu
        if (c < 4096) sm[c] = s;
        else {
            int cc = c - 4096;
            int hv = cc >> 7, d = cc & 127;
            vsb[((size_t)(b * NV + hv) * S_ + t) * 128 + d] = f2bf(s);
        }
    }
    __syncthreads();
    int grp = tid >> 3, l8 = tid & 7;
    float vals[16];
    float ss = 0.f;
    const float* sp = sm + grp * 128 + l8 * 16;
#pragma unroll
    for (int i = 0; i < 16; i++) { vals[i] = sp[i]; ss += vals[i] * vals[i]; }
    ss += __shfl_xor(ss, 1); ss += __shfl_xor(ss, 2); ss += __shfl_xor(ss, 4);
    float scale = rsqrtf(ss + 1e-6f);
    if (grp < 16) scale *= 0.08838834764831845f;  // DK^-0.5
    u16* op = (grp < 16 ? qsb : ksb) + ((size_t)(b * NK + (grp & 15)) * S_ + t) * 128 + l8 * 16;
    u16x8 o0, o1;
#pragma unroll
    for (int i = 0; i < 8; i++) { o0[i] = f2bf(vals[i] * scale); o1[i] = f2bf(vals[i + 8] * scale); }
    *(u16x8*)(op) = o0;
    *(u16x8*)(op + 8) = o1;
    if (tid < 32) {
        int hv = tid;
        float bval = ba[(size_t)token * 64 + (hv >> 1) * 4 + (hv & 1)];
        float aval = ba[(size_t)token * 64 + (hv >> 1) * 4 + 2 + (hv & 1)];
        float x = aval + dt_bias[hv];
        float sp2 = (x > 20.f) ? x : log1pf(__expf(x));
        float graw = -__expf(A_log[hv]) * sp2;
        float bt = 1.f / (1.f + __expf(-bval));
        gb2[(size_t)(b * NV + hv) * S_ + t] = make_float2(graw, bt);
    }
}

// ================= chunked delta rule =================
// chunk C=64. ch index = ((b*32+hv)*16 + chunk).

// ---- phase A1: decay factors, M (fp32), Mq/K'T/aQ (bf16), aC ----
__global__ __launch_bounds__(256) void k_prep(const u16* __restrict__ ksb, const u16* __restrict__ qsb,
                                              const float2* __restrict__ gb2, float* __restrict__ Mbuf,
                                              u16* __restrict__ MqB, u16* __restrict__ KtB,
                                              u16* __restrict__ aQB, float* __restrict__ aCB) {
    __shared__ u16 Kl[64 * 128];
    __shared__ u16 Ql[64 * 128];
    __shared__ float QKKK[64 * 68];
    __shared__ float cum[64], bet[64], aex[64], gl[64];
    int bid = blockIdx.x;
    int chunk = bid & 15, hv = (bid >> 4) & 31, b = bid >> 9;
    int hk = hv >> 1;
    size_t ch = bid;
    int tid = threadIdx.x, wid = tid >> 6, lane = tid & 63;
    int l15 = lane & 15, lg = lane >> 4;
    const u16* kg = ksb + ((size_t)(b * NK + hk) * S_ + chunk * 64) * 128;
    const u16* qg = qsb + ((size_t)(b * NK + hk) * S_ + chunk * 64) * 128;
    for (int c = wid; c < 32; c += 4) {
        const u16* src = (c < 16) ? kg : qg;
        u16* dst = (c < 16) ? Kl : Ql;
        int c1 = c & 15;
        int row = c1 * 4 + (lane >> 4);
        int g = lane & 15;
        gl16(src + row * 128 + ((g ^ (row & 7)) << 3), (char*)dst + c1 * 1024 + lane * 16);
    }
    if (tid < 64) {
        float2 gv = gb2[(size_t)(b * NV + hv) * S_ + chunk * 64 + tid];
        gl[tid] = gv.x; bet[tid] = gv.y;
    }
    __syncthreads();
    if (tid == 0) { float s = 0.f; for (int i = 0; i < 64; i++) { s += gl[i]; cum[i] = s; } }
    __syncthreads();
    if (tid < 64) aex[tid] = __expf(cum[tid]);
    // QK^T
    {
        f32x4 qk[4] = {};
#pragma unroll
        for (int kk = 0; kk < 4; kk++) {
            bf16x8 af = fragld(Ql, wid * 16 + l15, kk * 32 + lg * 8, 128);
#pragma unroll
            for (int nt = 0; nt < 4; nt++) {
                bf16x8 bk = fragld(Kl, nt * 16 + l15, kk * 32 + lg * 8, 128);
                qk[nt] = __builtin_amdgcn_mfma_f32_16x16x32_bf16(af, bk, qk[nt], 0, 0, 0);
            }
        }
#pragma unroll
        for (int nt = 0; nt < 4; nt++)
#pragma unroll
            for (int r = 0; r < 4; r++)
                QKKK[(wid * 16 + lg * 4 + r) * 68 + nt * 16 + l15] = qk[nt][r];
    }
    __syncthreads();
    {   // Mq[i][j] = (j<=i) exp(cum_i - cum_j) * QK[i][j]
        int i = tid >> 2, jc = (tid & 3) * 16;
        u16x8 m0, m1;
#pragma unroll
        for (int jj = 0; jj < 16; jj++) {
            int j = jc + jj;
            float v = (j <= i) ? __expf(cum[i] - cum[j]) * QKKK[i * 68 + j] : 0.f;
            if (jj < 8) m0[jj] = f2bf(v); else m1[jj - 8] = f2bf(v);
        }
        *(u16x8*)(MqB + ch * 4096 + i * 64 + jc) = m0;
        *(u16x8*)(MqB + ch * 4096 + i * 64 + jc + 8) = m1;
    }
    __syncthreads();
    // KK^T
    {
        f32x4 kkc[4] = {};
#pragma unroll
        for (int kk = 0; kk < 4; kk++) {
            bf16x8 af = fragld(Kl, wid * 16 + l15, kk * 32 + lg * 8, 128);
#pragma unroll
            for (int nt = 0; nt < 4; nt++) {
                bf16x8 bk = fragld(Kl, nt * 16 + l15, kk * 32 + lg * 8, 128);
                kkc[nt] = __builtin_amdgcn_mfma_f32_16x16x32_bf16(af, bk, kkc[nt], 0, 0, 0);
            }
        }
        __syncthreads();
#pragma unroll
        for (int nt = 0; nt < 4; nt++)
#pragma unroll
            for (int r = 0; r < 4; r++)
                QKKK[(wid * 16 + lg * 4 + r) * 68 + nt * 16 + l15] = kkc[nt][r];
    }
    __syncthreads();
    {   // M[i][j] = (j<i) beta_i exp(cum_i - cum_j) KK[i][j]  (fp32)
        int i = tid >> 2, jc = (tid & 3) * 16;
        float4 out4;
#pragma unroll
        for (int q4 = 0; q4 < 4; q4++) {
#pragma unroll
            for (int e = 0; e < 4; e++) {
                int j = jc + q4 * 4 + e;
                float v = (j < i) ? bet[i] * __expf(cum[i] - cum[j]) * QKKK[i * 68 + j] : 0.f;
                ((float*)&out4)[e] = v;
            }
            *(float4*)(Mbuf + ch * 4096 + i * 64 + jc + q4 * 4) = out4;
        }
    }
    {   // K'T[dk][j] = exp(cum_63 - cum_j) * K[j][dk]
        int dk = tid >> 1, jc = (tid & 1) * 32;
#pragma unroll
        for (int q8 = 0; q8 < 4; q8++) {
            u16x8 o;
#pragma unroll
            for (int e = 0; e < 8; e++) {
                int j = jc + q8 * 8 + e;
                o[e] = f2bf(__expf(cum[63] - cum[j]) * bf2f(Kl[swzidx(j, dk, 128)]));
            }
            *(u16x8*)(KtB + ch * 8192 + dk * 64 + jc + q8 * 8) = o;
        }
    }
    {   // aQ[i][dk] = exp(cum_i) * Q[i][dk]
        int i = tid >> 2, dc = (tid & 3) * 32;
        float a = aex[i];
#pragma unroll
        for (int q8 = 0; q8 < 4; q8++) {
            u16x8 o;
#pragma unroll
            for (int e = 0; e < 8; e++)
                o[e] = f2bf(a * bf2f(Ql[swzidx(i, dc + q8 * 8 + e, 128)]));
            *(u16x8*)(aQB + ch * 8192 + i * 128 + dc + q8 * 8) = o;
        }
    }
    if (tid == 0) aCB[ch] = aex[63];
}

// ---- phase A2: blocked forward substitution  X = (I+M)^{-1} [BV | -BaK] ----
__global__ __launch_bounds__(256) void k_solve(const u16* __restrict__ ksb, const u16* __restrict__ vsb,
                                               const float2* __restrict__ gb2, const float* __restrict__ Mbuf,
                                               float* __restrict__ TvB, u16* __restrict__ WB) {
    __shared__ float Ml[64 * 64];
    __shared__ u16 Kl[64 * 128];
    __shared__ u16 Vl[64 * 128];
    __shared__ u16 bounce[64 * 136];
    __shared__ float cum[64], bet[64], aex[64], gl[64];
    int bid = blockIdx.x;
    int chunk = bid & 15, hv = (bid >> 4) & 31, b = bid >> 9;
    int hk = hv >> 1;
    size_t ch = bid;
    int tid = threadIdx.x, wid = tid >> 6, lane = tid & 63;
    const u16* kg = ksb + ((size_t)(b * NK + hk) * S_ + chunk * 64) * 128;
    const u16* vg = vsb + ((size_t)(b * NV + hv) * S_ + chunk * 64) * 128;
    const float* mg = Mbuf + ch * 4096;
    for (int c = wid; c < 48; c += 4) {
        if (c < 16) gl16((const char*)mg + c * 1024 + lane * 16, (char*)Ml + c * 1024 + lane * 16);
        else if (c < 32) gl16((const char*)kg + (c - 16) * 1024 + lane * 16, (char*)Kl + (c - 16) * 1024 + lane * 16);
        else gl16((const char*)vg + (c - 32) * 1024 + lane * 16, (char*)Vl + (c - 32) * 1024 + lane * 16);
    }
    if (tid < 64) {
        float2 gv = gb2[(size_t)(b * NV + hv) * S_ + chunk * 64 + tid];
        gl[tid] = gv.x; bet[tid] = gv.y;
    }
    __syncthreads();
    if (tid == 0) { float s = 0.f; for (int i = 0; i < 64; i++) { s += gl[i]; cum[i] = s; } }
    __syncthreads();
    if (tid < 64) aex[tid] = __expf(cum[tid]);
    __syncthreads();
    int c = tid;
    float X[64];
    if (c < 128) {
#pragma unroll
        for (int i = 0; i < 64; i++) X[i] = bet[i] * bf2f(Vl[i * 128 + c]);
    } else {
        int d = c - 128;
#pragma unroll
        for (int i = 0; i < 64; i++) X[i] = -bet[i] * aex[i] * bf2f(Kl[i * 128 + d]);
    }
#pragma unroll
    for (int IB = 0; IB < 8; ++IB) {
#pragma unroll
        for (int JB = 0; JB < IB; ++JB) {
#pragma unroll
            for (int ii = 0; ii < 8; ++ii) {
                const float* mr = &Ml[(IB * 8 + ii) * 64 + JB * 8];
                float4 a = *(const float4*)mr, bq = *(const float4*)(mr + 4);
                float x = X[IB * 8 + ii];
                x = fmaf(-a.x, X[JB * 8 + 0], x); x = fmaf(-a.y, X[JB * 8 + 1], x);
                x = fmaf(-a.z, X[JB * 8 + 2], x); x = fmaf(-a.w, X[JB * 8 + 3], x);
                x = fmaf(-bq.x, X[JB * 8 + 4], x); x = fmaf(-bq.y, X[JB * 8 + 5], x);
                x = fmaf(-bq.z, X[JB * 8 + 6], x); x = fmaf(-bq.w, X[JB * 8 + 7], x);
                X[IB * 8 + ii] = x;
            }
        }
#pragma unroll
        for (int ii = 1; ii < 8; ++ii) {
            float x = X[IB * 8 + ii];
#pragma unroll
            for (int jj = 0; jj < ii; ++jj)
                x = fmaf(-Ml[(IB * 8 + ii) * 64 + IB * 8 + jj], X[IB * 8 + jj], x);
            X[IB * 8 + ii] = x;
        }
    }
    if (c < 128) {
        float* o = TvB + ch * 8192 + (size_t)c * 64;
#pragma unroll
        for (int q4 = 0; q4 < 16; q4++) {
            float4 v4 = { X[q4 * 4], X[q4 * 4 + 1], X[q4 * 4 + 2], X[q4 * 4 + 3] };
            *(float4*)(o + q4 * 4) = v4;
        }
    } else {
        int d = c - 128;
#pragma unroll
        for (int i = 0; i < 64; i++) bounce[i * 136 + d] = f2bf(X[i]);
    }
    __syncthreads();
    {
        int i = tid >> 2, dc = (tid & 3) * 32;
#pragma unroll
        for (int q8 = 0; q8 < 4; q8++) {
            u16x8 o;
#pragma unroll
            for (int e = 0; e < 8; e++) o[e] = bounce[i * 136 + dc + q8 * 8 + e];
            *(u16x8*)(WB + ch * 8192 + i * 128 + dc + q8 * 8) = o;
        }
    }
}

// ---- phase B: sequential chunks, state in LDS (bf16 hi+lo), all-MFMA ----
__global__ __launch_bounds__(256) void k_chunk(const float* __restrict__ TvB, const u16* __restrict__ WB,
                                               const u16* __restrict__ aQB, const u16* __restrict__ MqB,
                                               const u16* __restrict__ KtB, const float* __restrict__ aCB,
                                               float* __restrict__ core) {
    __shared__ u16 S0h[64 * 128], S0l[64 * 128];
    __shared__ u16 DTh[64 * 64], DTl[64 * 64];
    __shared__ float Tvl[64 * 64];
    __shared__ u16 Wl[64 * 128], aQl[64 * 128];
    __shared__ u16 Mql[64 * 64];
    __shared__ u16 Ktl[128 * 64];
    int bid = blockIdx.x;
    int split = bid & 1, bh = bid >> 1;
    int tid = threadIdx.x, wid = tid >> 6, lane = tid & 63;
    int l15 = lane & 15, lg = lane >> 4;
    float4 z4 = {0.f, 0.f, 0.f, 0.f};
    for (int i = tid; i < 64 * 128 / 8; i += 256) {
        *(float4*)(S0h + i * 8) = z4;
        *(float4*)(S0l + i * 8) = z4;
    }
    for (int chunk = 0; chunk < 16; ++chunk) {
        size_t ch = (size_t)bh * 16 + chunk;
        const char* tvg = (const char*)(TvB + ch * 8192 + (size_t)split * 64 * 64);
        const char* wg = (const char*)(WB + ch * 8192);
        const char* qg = (const char*)(aQB + ch * 8192);
        const char* mg = (const char*)(MqB + ch * 4096);
        const char* kg = (const char*)(KtB + ch * 8192);
        for (int c = wid; c < 72; c += 4) {
            if (c < 16) {
                gl16(tvg + c * 1024 + lane * 16, (char*)Tvl + c * 1024 + lane * 16);
            } else if (c < 32) {
                int cc = c - 16; int row = cc * 4 + (lane >> 4); int g = lane & 15;
                gl16(wg + row * 256 + ((g ^ (row & 7)) << 4), (char*)Wl + cc * 1024 + lane * 16);
            } else if (c < 48) {
                int cc = c - 32; int row = cc * 4 + (lane >> 4); int g = lane & 15;
                gl16(qg + row * 256 + ((g ^ (row & 7)) << 4), (char*)aQl + cc * 1024 + lane * 16);
            } else if (c < 56) {
                int cc = c - 48; int row = cc * 8 + (lane >> 3); int g = lane & 7;
                gl16(mg + row * 128 + ((g ^ (row & 7)) << 4), (char*)Mql + cc * 1024 + lane * 16);
            } else {
                int cc = c - 56; int row = cc * 8 + (lane >> 3); int g = lane & 7;
                gl16(kg + row * 128 + ((g ^ (row & 7)) << 4), (char*)Ktl + cc * 1024 + lane * 16);
            }
        }
        float aC = aCB[ch];
        __syncthreads();
        f32x4 Dacc[4], Oacc[4] = {};
#pragma unroll
        for (int nt = 0; nt < 4; nt++)
#pragma unroll
            for (int r = 0; r < 4; r++)
                Dacc[nt][r] = Tvl[(wid * 16 + lg * 4 + r) * 64 + nt * 16 + l15];
#pragma unroll
        for (int kk = 0; kk < 4; kk++) {
            bf16x8 aH = fragld(S0h, wid * 16 + l15, kk * 32 + lg * 8, 128);
            bf16x8 aL = fragld(S0l, wid * 16 + l15, kk * 32 + lg * 8, 128);
#pragma unroll
            for (int nt = 0; nt < 4; nt++) {
                bf16x8 bW = fragld(Wl, nt * 16 + l15, kk * 32 + lg * 8, 128);
                Dacc[nt] = __builtin_amdgcn_mfma_f32_16x16x32_bf16(aH, bW,
                           __builtin_amdgcn_mfma_f32_16x16x32_bf16(aL, bW, Dacc[nt], 0, 0, 0), 0, 0, 0);
                bf16x8 bQ = fragld(aQl, nt * 16 + l15, kk * 32 + lg * 8, 128);
                Oacc[nt] = __builtin_amdgcn_mfma_f32_16x16x32_bf16(aH, bQ,
                           __builtin_amdgcn_mfma_f32_16x16x32_bf16(aL, bQ, Oacc[nt], 0, 0, 0), 0, 0, 0);
            }
        }
#pragma unroll
        for (int nt = 0; nt < 4; nt++)
#pragma unroll
            for (int r = 0; r < 4; r++) {
                int dv = wid * 16 + lg * 4 + r, t = nt * 16 + l15;
                float x = Dacc[nt][r];
                u16 h = f2bf(x);
                int idx = swzidx(dv, t, 64);
                DTh[idx] = h; DTl[idx] = f2bf(x - bf2f(h));
            }
#pragma unroll
        for (int kk2 = 0; kk2 < 2; kk2++) {
            bf16x8 aDh = fragld(DTh, wid * 16 + l15, kk2 * 32 + lg * 8, 64);
            bf16x8 aDl = fragld(DTl, wid * 16 + l15, kk2 * 32 + lg * 8, 64);
#pragma unroll
            for (int nt = 0; nt < 4; nt++) {
                bf16x8 bM = fragld(Mql, nt * 16 + l15, kk2 * 32 + lg * 8, 64);
                Oacc[nt] = __builtin_amdgcn_mfma_f32_16x16x32_bf16(aDh, bM,
                           __builtin_amdgcn_mfma_f32_16x16x32_bf16(aDl, bM, Oacc[nt], 0, 0, 0), 0, 0, 0);
            }
        }
#pragma unroll
        for (int nt = 0; nt < 4; nt++) {
            float4 o = { Oacc[nt][0], Oacc[nt][1], Oacc[nt][2], Oacc[nt][3] };
            size_t t = (size_t)chunk * 64 + nt * 16 + l15;
            *(float4*)(core + ((size_t)bh * S_ + t) * 128 + split * 64 + wid * 16 + lg * 4) = o;
        }
        f32x4 Sacc[8] = {};
#pragma unroll
        for (int kk2 = 0; kk2 < 2; kk2++) {
            bf16x8 aDh = fragld(DTh, wid * 16 + l15, kk2 * 32 + lg * 8, 64);
            bf16x8 aDl = fragld(DTl, wid * 16 + l15, kk2 * 32 + lg * 8, 64);
#pragma unroll
            for (int nd = 0; nd < 8; nd++) {
                bf16x8 bK = fragld(Ktl, nd * 16 + l15, kk2 * 32 + lg * 8, 64);
                Sacc[nd] = __builtin_amdgcn_mfma_f32_16x16x32_bf16(aDh, bK,
                           __builtin_amdgcn_mfma_f32_16x16x32_bf16(aDl, bK, Sacc[nd], 0, 0, 0), 0, 0, 0);
            }
        }
#pragma unroll
        for (int nd = 0; nd < 8; nd++)
#pragma unroll
            for (int r = 0; r < 4; r++) {
                int dv = wid * 16 + lg * 4 + r, dk = nd * 16 + l15;
                int idx = swzidx(dv, dk, 128);
                float old = bf2f(S0h[idx]) + bf2f(S0l[idx]);
                float nu = fmaf(aC, old, Sacc[nd][r]);
                u16 h = f2bf(nu);
                S0h[idx] = h; S0l[idx] = f2bf(nu - bf2f(h));
            }
        __syncthreads();
    }
}

// ---------------- RMS-norm * norm_weight * silu(z) -> bf16 ----------------
__global__ __launch_bounds__(256) void k_gate(const float* __restrict__ core, const u16* __restrict__ qkvz,
                                              const float* __restrict__ nw, u16* __restrict__ gated) {
    int token = blockIdx.x, tid = threadIdx.x;
    int b = token >> 10, t = token & (S_ - 1);
    int grp = tid >> 3, l8 = tid & 7;
    const float* cp = core + ((size_t)(b * NV + grp) * S_ + t) * DV_ + l8 * 16;
    float vals[16];
    float ss = 0.f;
#pragma unroll
    for (int i = 0; i < 16; i++) { vals[i] = cp[i]; ss += vals[i] * vals[i]; }
    ss += __shfl_xor(ss, 1); ss += __shfl_xor(ss, 2); ss += __shfl_xor(ss, 4);
    float rms = rsqrtf(ss * (1.0f / DV_) + 1e-6f);
    const u16* zp = qkvz + (size_t)token * QKVZ_N + (grp >> 1) * 768 + 512 + (grp & 1) * 128 + l8 * 16;
    u16* op = gated + ((size_t)token * NV + grp) * DV_ + l8 * 16;
#pragma unroll
    for (int i = 0; i < 16; i++) {
        float z = bf2f(zp[i]);
        float sz = z / (1.f + __expf(-z));
        op[i] = f2bf(vals[i] * rms * nw[l8 * 16 + i] * sz);
    }
}

extern "C" void kernel_launch(void* const* d_in, const int* in_sizes, int n_in,
                              void* d_out, int out_size, void* d_ws, size_t ws_size,
                              hipStream_t stream) {
    const float* hidden = (const float*)d_in[0];
    const float* Wqkvz = (const float*)d_in[1];
    const float* Wba = (const float*)d_in[2];
    const float* convw = (const float*)d_in[3];
    const float* A_log = (const float*)d_in[4];
    const float* dt_bias = (const float*)d_in[5];
    const float* norm_w = (const float*)d_in[6];
    const float* Wout = (const float*)d_in[7];

    char* ws = (char*)d_ws;
    size_t off = 0;
    auto alloc = [&](size_t bytes) -> void* {
        void* p = ws + off;
        off += (bytes + 255) & ~(size_t)255;
        return p;
    };
    u16* hiddenB = (u16*)alloc((size_t)TOK * HID * 2);
    u16* WqT = (u16*)alloc((size_t)QKVZ_N * HID * 2);
    u16* WoT = (u16*)alloc((size_t)HID * 4096 * 2);
    u16* qkvz = (u16*)alloc((size_t)TOK * QKVZ_N * 2);
    float* ba = (float*)alloc((size_t)TOK * 64 * 4);
    u16* qsb = (u16*)alloc((size_t)B_ * NK * S_ * 128 * 2);
    u16* ksb = (u16*)alloc((size_t)B_ * NK * S_ * 128 * 2);
    u16* vsb = (u16*)alloc((size_t)B_ * NV * S_ * 128 * 2);
    float2* gb2 = (float2*)alloc((size_t)B_ * NV * S_ * 8);
    float* Mbuf = (float*)alloc((size_t)1024 * 4096 * 4);
    u16* MqB = (u16*)alloc((size_t)1024 * 4096 * 2);
    u16* KtB = (u16*)alloc((size_t)1024 * 8192 * 2);
    u16* aQB = (u16*)alloc((size_t)1024 * 8192 * 2);
    float* TvB = (float*)alloc((size_t)1024 * 8192 * 4);
    u16* WB = (u16*)alloc((size_t)1024 * 8192 * 2);
    float* aCB = (float*)alloc((size_t)1024 * 4);
    float* core = (float*)alloc((size_t)B_ * NV * S_ * 128 * 4);
    u16* gated = (u16*)alloc((size_t)TOK * 4096 * 2);

    k_cvt_bf16<<<4096, 256, 0, stream>>>(hidden, hiddenB, TOK * HID);
    k_transpose<<<dim3(QKVZ_N / 32, HID / 32), dim3(32, 8), 0, stream>>>(Wqkvz, WqT, HID, QKVZ_N);
    k_transpose<<<dim3(HID / 32, 4096 / 32), dim3(32, 8), 0, stream>>>(Wout, WoT, 4096, HID);
    k_gemm256<<<768, 256, 0, stream>>>(hiddenB, WqT, qkvz, HID, QKVZ_N);
    k_ba<<<TOK, 64, 0, stream>>>(hidden, Wba, ba);
    k_conv<<<TOK, 256, 0, stream>>>(qkvz, ba, convw, A_log, dt_bias, qsb, ksb, vsb, gb2);
    k_prep<<<1024, 256, 0, stream>>>(ksb, qsb, gb2, Mbuf, MqB, KtB, aQB, aCB);
    k_solve<<<1024, 256, 0, stream>>>(ksb, vsb, gb2, Mbuf, TvB, WB);
    k_chunk<<<128, 256, 0, stream>>>(TvB, WB, aQB, MqB, KtB, aCB, core);
    k_gate<<<TOK, 256, 0, stream>>>(core, qkvz, norm_w, gated);
    k_gemm<0><<<dim3(HID / 128, TOK / 128), 256, 0, stream>>>(gated, WoT, d_out, 4096, HID);
}

// Round 12
// 556.325 us; speedup vs baseline: 1.0450x; 1.0450x over previous
//
#include <hip/hip_runtime.h>
#include <stdint.h>

#define B_ 2
#define S_ 1024
#define HID 2048
#define NK 16
#define NV 32
#define DK_ 128
#define DV_ 128
#define QKVZ_N 12288
#define TOK (B_*S_)

typedef unsigned short u16;
typedef __bf16 bf16x8 __attribute__((ext_vector_type(8)));
typedef float f32x4 __attribute__((ext_vector_type(4)));
typedef unsigned short u16x8 __attribute__((ext_vector_type(8)));
typedef unsigned short u16x4 __attribute__((ext_vector_type(4)));

__device__ __forceinline__ float bf2f(u16 u) {
    return __builtin_bit_cast(float, (unsigned)u << 16);
}
__device__ __forceinline__ u16 f2bf(float f) {
    unsigned u = __builtin_bit_cast(unsigned, f);
    u += 0x7fff + ((u >> 16) & 1);
    return (u16)(u >> 16);
}

// async global -> LDS. LDS dest: wave-uniform base + lane*16; global src per-lane.
__device__ __forceinline__ void gl16(const void* g, void* l) {
    __builtin_amdgcn_global_load_lds((const __attribute__((address_space(1))) uint32_t*)g,
                                     (__attribute__((address_space(3))) uint32_t*)l, 16, 0, 0);
}

// Swizzled LDS fragment read (XOR row&7 on 16B granules).
__device__ __forceinline__ bf16x8 fragld(const u16* base, int row, int col, int rowhw) {
    int idx = row * rowhw + ((((col >> 3) ^ (row & 7))) << 3);
    return __builtin_bit_cast(bf16x8, *(const u16x8*)(base + idx));
}
__device__ __forceinline__ int swzidx(int row, int col, int rowhw) {
    return row * rowhw + (((col >> 3) ^ (row & 7)) << 3) + (col & 7);
}

// ---------------- fp32 -> bf16 elementwise ----------------
__global__ void k_cvt_bf16(const float* __restrict__ in, u16* __restrict__ out, int n) {
    int i = (blockIdx.x * blockDim.x + threadIdx.x) * 4;
    if (i >= n) return;
    float4 v = *(const float4*)(in + i);
    u16x4 o = { f2bf(v.x), f2bf(v.y), f2bf(v.z), f2bf(v.w) };
    *(u16x4*)(out + i) = o;
}

// ---------------- fp32 (R,C) -> bf16 (C,R) tiled transpose ----------------
__global__ void k_transpose(const float* __restrict__ in, u16* __restrict__ out, int R, int C) {
    __shared__ float tile[32][33];
    int c0 = blockIdx.x * 32, r0 = blockIdx.y * 32;
    int tx = threadIdx.x, ty = threadIdx.y;  // (32,8)
#pragma unroll
    for (int i = 0; i < 4; i++)
        tile[ty + i * 8][tx] = in[(size_t)(r0 + ty + i * 8) * C + c0 + tx];
    __syncthreads();
#pragma unroll
    for (int i = 0; i < 4; i++)
        out[(size_t)(c0 + ty + i * 8) * R + r0 + tx] = f2bf(tile[tx][ty + i * 8]);
}

// ---------------- 256x128 bf16 GEMM, 8 waves (4M x 2N), counted-vmcnt pipeline ----------------
// R9 geometry (113 us / 913 TF) + R11's race-free boundary:
//   s_waitcnt vmcnt(3) lgkmcnt(0)  -> tile-t loads landed AND my ds_reads executed
//   s_barrier                      -> published
//   sched_barrier(0)               -> stage gl16s can't hoist above the barrier
// 3 LDS bufs (24KB) rotate mod 3; during tile t stage t+2; per-wave 3 loads/stage.
__global__ __launch_bounds__(512) void k_gemm256(const u16* __restrict__ A, const u16* __restrict__ Bt,
                                                 u16* __restrict__ C, int K, int ldc) {
    __shared__ u16 lds[3 * 12288];  // buf b: A (8192 u16) at b*12288, B (4096 u16) at +8192
    int tid = threadIdx.x, wid = tid >> 6, lane = tid & 63;
    int wm = wid >> 1, wn = wid & 1;
    int l15 = lane & 15, lg = lane >> 4;
    int L = blockIdx.x;
    int xcd = L & 7, j = L >> 3;
    int bn = xcd * 12 + (j >> 3);
    int bm = j & 7;
    const u16* Ag = A + (size_t)bm * 256 * K;
    const u16* Bg = Bt + (size_t)bn * 128 * K;

    // per-row granule rotation: lds granule p holds global granule (p + 4 - (row>>1)) & 3.
    auto stage = [&](int t, int b) {
        u16* basebuf = &lds[b * 12288];
        int kcol = t * 32;
#pragma unroll
        for (int jj = 0; jj < 2; jj++) {
            int chunk = wid * 2 + jj;      // 16 A chunks (16 rows x 32 cols each)
            int row = chunk * 16 + (lane >> 2);
            int gg = ((lane & 3) + 4 - ((row >> 1) & 3)) & 3;
            gl16(Ag + (size_t)row * K + kcol + gg * 8, (char*)basebuf + chunk * 1024);
        }
        {
            int chunk = wid;               // 8 B chunks
            int row = chunk * 16 + (lane >> 2);
            int gg = ((lane & 3) + 4 - ((row >> 1) & 3)) & 3;
            gl16(Bg + (size_t)row * K + kcol + gg * 8, (char*)(basebuf + 8192) + chunk * 1024);
        }
    };
    auto ldfA = [&](int bsel, int row) -> bf16x8 {
        const u16* p = &lds[bsel * 12288];
        int g = (lg + (row >> 1)) & 3;
        return __builtin_bit_cast(bf16x8, *(const u16x8*)(p + row * 32 + g * 8));
    };
    auto ldfB = [&](int bsel, int row) -> bf16x8 {
        const u16* p = &lds[bsel * 12288 + 8192];
        int g = (lg + (row >> 1)) & 3;
        return __builtin_bit_cast(bf16x8, *(const u16x8*)(p + row * 32 + g * 8));
    };

    f32x4 acc[4][4] = {};
    int NT = K >> 5;
    stage(0, 0);
    stage(1, 1);
    for (int t = 0; t < NT; ++t) {
        if (t < NT - 1) asm volatile("s_waitcnt vmcnt(3) lgkmcnt(0)" ::: "memory");
        else            asm volatile("s_waitcnt vmcnt(0) lgkmcnt(0)" ::: "memory");
        __builtin_amdgcn_s_barrier();
        __builtin_amdgcn_sched_barrier(0);
        if (t + 2 < NT) stage(t + 2, (t + 2) % 3);
        int bsel = t % 3;
        bf16x8 bfr[4];
#pragma unroll
        for (int ni = 0; ni < 4; ni++) bfr[ni] = ldfB(bsel, wn * 64 + ni * 16 + l15);
        __builtin_amdgcn_s_setprio(1);
#pragma unroll
        for (int mi = 0; mi < 4; mi++) {
            bf16x8 af = ldfA(bsel, wm * 64 + mi * 16 + l15);
#pragma unroll
            for (int ni = 0; ni < 4; ni++)
                acc[mi][ni] = __builtin_amdgcn_mfma_f32_16x16x32_bf16(af, bfr[ni], acc[mi][ni], 0, 0, 0);
        }
        __builtin_amdgcn_s_setprio(0);
    }
#pragma unroll
    for (int mi = 0; mi < 4; mi++) {
        int gr0 = bm * 256 + wm * 64 + mi * 16 + lg * 4;
#pragma unroll
        for (int ni = 0; ni < 4; ni++) {
            int gc = bn * 128 + wn * 64 + ni * 16 + l15;
#pragma unroll
            for (int r = 0; r < 4; r++)
                C[(size_t)(gr0 + r) * ldc + gc] = f2bf(acc[mi][ni][r]);
        }
    }
}

// ---------------- bf16 GEMM: 128x128 (output projection) ----------------
template <int OUT_BF16>
__global__ __launch_bounds__(256) void k_gemm(const u16* __restrict__ A, const u16* __restrict__ Bt,
                                              void* __restrict__ Cv, int K, int ldc) {
    __shared__ u16 As[128 * 32];
    __shared__ u16 Bs[128 * 32];
    int tid = threadIdx.x;
    int bm = blockIdx.y, bn = blockIdx.x;
    int wid = tid >> 6, lane = tid & 63;
    int wm = wid >> 1, wn = wid & 1;
    int l15 = lane & 15, lg = lane >> 4;
    const u16* src0 = (wid >> 1) ? (Bt + (size_t)bn * 128 * K) : (A + (size_t)bm * 128 * K);
    u16* ldsb = (wid >> 1) ? Bs : As;
    int cbase = (wid & 1) * 4;
    int lrow = lane >> 2, lcol = (lane & 3) * 8;
    f32x4 acc[4][4] = {};
    for (int k0 = 0; k0 < K; k0 += 32) {
        if (k0) __syncthreads();
#pragma unroll
        for (int c = 0; c < 4; c++) {
            int ch = cbase + c;
            gl16(src0 + (size_t)(16 * ch + lrow) * K + k0 + lcol, (char*)ldsb + ch * 1024);
        }
        __syncthreads();
        bf16x8 af[4], bf[4];
#pragma unroll
        for (int mi = 0; mi < 4; mi++)
            af[mi] = __builtin_bit_cast(bf16x8, *(const u16x8*)&As[(wm * 64 + mi * 16 + l15) * 32 + lg * 8]);
#pragma unroll
        for (int ni = 0; ni < 4; ni++)
            bf[ni] = __builtin_bit_cast(bf16x8, *(const u16x8*)&Bs[(wn * 64 + ni * 16 + l15) * 32 + lg * 8]);
#pragma unroll
        for (int mi = 0; mi < 4; mi++)
#pragma unroll
            for (int ni = 0; ni < 4; ni++)
                acc[mi][ni] = __builtin_amdgcn_mfma_f32_16x16x32_bf16(af[mi], bf[ni], acc[mi][ni], 0, 0, 0);
    }
#pragma unroll
    for (int mi = 0; mi < 4; mi++) {
        int gr0 = bm * 128 + wm * 64 + mi * 16 + lg * 4;
#pragma unroll
        for (int ni = 0; ni < 4; ni++) {
            int gc = bn * 128 + wn * 64 + ni * 16 + l15;
#pragma unroll
            for (int r = 0; r < 4; r++) {
                if (OUT_BF16)
                    ((u16*)Cv)[(size_t)(gr0 + r) * ldc + gc] = f2bf(acc[mi][ni][r]);
                else
                    ((float*)Cv)[(size_t)(gr0 + r) * ldc + gc] = acc[mi][ni][r];
            }
        }
    }
}

// ---------------- ba = hidden @ W_ba (fp32, N=64) ----------------
__global__ void k_ba(const float* __restrict__ hid, const float* __restrict__ Wba, float* __restrict__ ba) {
    int token = blockIdx.x;
    int c = threadIdx.x;
    const float* h = hid + (size_t)token * HID;
    const float* w = Wba + c;
    float acc = 0.f;
    for (int k = 0; k < HID; k += 4) {
        float4 hv = *(const float4*)(h + k);
        acc += hv.x * w[(size_t)k * 64] + hv.y * w[(size_t)(k + 1) * 64] +
               hv.z * w[(size_t)(k + 2) * 64] + hv.w * w[(size_t)(k + 3) * 64];
    }
    ba[(size_t)token * 64 + c] = acc;
}

// ---------------- causal depthwise conv4 + silu + l2norm -> bf16 + {g_raw,beta} ----------------
__global__ __launch_bounds__(256) void k_conv(const u16* __restrict__ qkvz, const float* __restrict__ ba,
                                              const float* __restrict__ cw, const float* __restrict__ A_log,
                                              const float* __restrict__ dt_bias, u16* __restrict__ qsb,
                                              u16* __restrict__ ksb, u16* __restrict__ vsb,
                                              float2* __restrict__ gb2) {
    __shared__ float sm[4096];
    int token = blockIdx.x;
    int b = token >> 10;
    int t = token & (S_ - 1);
    int tid = threadIdx.x;
    const u16* row3 = qkvz + (size_t)token * QKVZ_N;
#pragma unroll
    for (int i = 0; i < 32; i++) {
        int c = tid + i * 256;
        int col;
        if (c < 2048) col = (c >> 7) * 768 + (c & 127);
        else if (c < 4096) col = ((c - 2048) >> 7) * 768 + 128 + (c & 127);
        else {
            int cc = c - 4096;
            col = (cc >> 8) * 768 + 256 + ((cc >> 7) & 1) * 128 + (cc & 127);
        }
        float4 w = *(const float4*)(cw + c * 4);
        float x3 = bf2f(row3[col]);
        float x2 = (t >= 1) ? bf2f(row3[col - QKVZ_N]) : 0.f;
        float x1 = (t >= 2) ? bf2f(row3[col - 2 * QKVZ_N]) : 0.f;
        float x0 = (t >= 3) ? bf2f(row3[col - 3 * QKVZ_N]) : 0.f;
        float s = w.x * x0 + w.y * x1 + w.z * x2 + w.w * x3;
        s = s / (1.f + __expf(-s));  // silu
        if (c < 4096) sm[c] = s;
        else {
            int cc = c - 4096;
            int hv = cc >> 7, d = cc & 127;
            vsb[((size_t)(b * NV + hv) * S_ + t) * 128 + d] = f2bf(s);
        }
    }
    __syncthreads();
    int grp = tid >> 3, l8 = tid & 7;
    float vals[16];
    float ss = 0.f;
    const float* sp = sm + grp * 128 + l8 * 16;
#pragma unroll
    for (int i = 0; i < 16; i++) { vals[i] = sp[i]; ss += vals[i] * vals[i]; }
    ss += __shfl_xor(ss, 1); ss += __shfl_xor(ss, 2); ss += __shfl_xor(ss, 4);
    float scale = rsqrtf(ss + 1e-6f);
    if (grp < 16) scale *= 0.08838834764831845f;  // DK^-0.5
    u16* op = (grp < 16 ? qsb : ksb) + ((size_t)(b * NK + (grp & 15)) * S_ + t) * 128 + l8 * 16;
    u16x8 o0, o1;
#pragma unroll
    for (int i = 0; i < 8; i++) { o0[i] = f2bf(vals[i] * scale); o1[i] = f2bf(vals[i + 8] * scale); }
    *(u16x8*)(op) = o0;
    *(u16x8*)(op + 8) = o1;
    if (tid < 32) {
        int hv = tid;
        float bval = ba[(size_t)token * 64 + (hv >> 1) * 4 + (hv & 1)];
        float aval = ba[(size_t)token * 64 + (hv >> 1) * 4 + 2 + (hv & 1)];
        float x = aval + dt_bias[hv];
        float sp2 = (x > 20.f) ? x : log1pf(__expf(x));
        float graw = -__expf(A_log[hv]) * sp2;
        float bt = 1.f / (1.f + __expf(-bval));
        gb2[(size_t)(b * NV + hv) * S_ + t] = make_float2(graw, bt);
    }
}

// ================= chunked delta rule =================
// chunk C=64. ch index = ((b*32+hv)*16 + chunk).

// ---- phase A1: decay factors, M (fp32), Mq/K'T/aQ (bf16), aC ----
__global__ __launch_bounds__(256) void k_prep(const u16* __restrict__ ksb, const u16* __restrict__ qsb,
                                              const float2* __restrict__ gb2, float* __restrict__ Mbuf,
                                              u16* __restrict__ MqB, u16* __restrict__ KtB,
                                              u16* __restrict__ aQB, float* __restrict__ aCB) {
    __shared__ u16 Kl[64 * 128];
    __shared__ u16 Ql[64 * 128];
    __shared__ float QKKK[64 * 68];
    __shared__ float cum[64], bet[64], aex[64], gl[64];
    int bid = blockIdx.x;
    int chunk = bid & 15, hv = (bid >> 4) & 31, b = bid >> 9;
    int hk = hv >> 1;
    size_t ch = bid;
    int tid = threadIdx.x, wid = tid >> 6, lane = tid & 63;
    int l15 = lane & 15, lg = lane >> 4;
    const u16* kg = ksb + ((size_t)(b * NK + hk) * S_ + chunk * 64) * 128;
    const u16* qg = qsb + ((size_t)(b * NK + hk) * S_ + chunk * 64) * 128;
    for (int c = wid; c < 32; c += 4) {
        const u16* src = (c < 16) ? kg : qg;
        u16* dst = (c < 16) ? Kl : Ql;
        int c1 = c & 15;
        int row = c1 * 4 + (lane >> 4);
        int g = lane & 15;
        gl16(src + row * 128 + ((g ^ (row & 7)) << 3), (char*)dst + c1 * 1024 + lane * 16);
    }
    if (tid < 64) {
        float2 gv = gb2[(size_t)(b * NV + hv) * S_ + chunk * 64 + tid];
        gl[tid] = gv.x; bet[tid] = gv.y;
    }
    __syncthreads();
    if (tid == 0) { float s = 0.f; for (int i = 0; i < 64; i++) { s += gl[i]; cum[i] = s; } }
    __syncthreads();
    if (tid < 64) aex[tid] = __expf(cum[tid]);
    // QK^T
    {
        f32x4 qk[4] = {};
#pragma unroll
        for (int kk = 0; kk < 4; kk++) {
            bf16x8 af = fragld(Ql, wid * 16 + l15, kk * 32 + lg * 8, 128);
#pragma unroll
            for (int nt = 0; nt < 4; nt++) {
                bf16x8 bk = fragld(Kl, nt * 16 + l15, kk * 32 + lg * 8, 128);
                qk[nt] = __builtin_amdgcn_mfma_f32_16x16x32_bf16(af, bk, qk[nt], 0, 0, 0);
            }
        }
#pragma unroll
        for (int nt = 0; nt < 4; nt++)
#pragma unroll
            for (int r = 0; r < 4; r++)
                QKKK[(wid * 16 + lg * 4 + r) * 68 + nt * 16 + l15] = qk[nt][r];
    }
    __syncthreads();
    {   // Mq[i][j] = (j<=i) exp(cum_i - cum_j) * QK[i][j]
        int i = tid >> 2, jc = (tid & 3) * 16;
        u16x8 m0, m1;
#pragma unroll
        for (int jj = 0; jj < 16; jj++) {
            int j = jc + jj;
            float v = (j <= i) ? __expf(cum[i] - cum[j]) * QKKK[i * 68 + j] : 0.f;
            if (jj < 8) m0[jj] = f2bf(v); else m1[jj - 8] = f2bf(v);
        }
        *(u16x8*)(MqB + ch * 4096 + i * 64 + jc) = m0;
        *(u16x8*)(MqB + ch * 4096 + i * 64 + jc + 8) = m1;
    }
    __syncthreads();
    // KK^T
    {
        f32x4 kkc[4] = {};
#pragma unroll
        for (int kk = 0; kk < 4; kk++) {
            bf16x8 af = fragld(Kl, wid * 16 + l15, kk * 32 + lg * 8, 128);
#pragma unroll
            for (int nt = 0; nt < 4; nt++) {
                bf16x8 bk = fragld(Kl, nt * 16 + l15, kk * 32 + lg * 8, 128);
                kkc[nt] = __builtin_amdgcn_mfma_f32_16x16x32_bf16(af, bk, kkc[nt], 0, 0, 0);
            }
        }
        __syncthreads();
#pragma unroll
        for (int nt = 0; nt < 4; nt++)
#pragma unroll
            for (int r = 0; r < 4; r++)
                QKKK[(wid * 16 + lg * 4 + r) * 68 + nt * 16 + l15] = kkc[nt][r];
    }
    __syncthreads();
    {   // M[i][j] = (j<i) beta_i exp(cum_i - cum_j) KK[i][j]  (fp32)
        int i = tid >> 2, jc = (tid & 3) * 16;
        float4 out4;
#pragma unroll
        for (int q4 = 0; q4 < 4; q4++) {
#pragma unroll
            for (int e = 0; e < 4; e++) {
                int j = jc + q4 * 4 + e;
                float v = (j < i) ? bet[i] * __expf(cum[i] - cum[j]) * QKKK[i * 68 + j] : 0.f;
                ((float*)&out4)[e] = v;
            }
            *(float4*)(Mbuf + ch * 4096 + i * 64 + jc + q4 * 4) = out4;
        }
    }
    {   // K'T[dk][j] = exp(cum_63 - cum_j) * K[j][dk]
        int dk = tid >> 1, jc = (tid & 1) * 32;
#pragma unroll
        for (int q8 = 0; q8 < 4; q8++) {
            u16x8 o;
#pragma unroll
            for (int e = 0; e < 8; e++) {
                int j = jc + q8 * 8 + e;
                o[e] = f2bf(__expf(cum[63] - cum[j]) * bf2f(Kl[swzidx(j, dk, 128)]));
            }
            *(u16x8*)(KtB + ch * 8192 + dk * 64 + jc + q8 * 8) = o;
        }
    }
    {   // aQ[i][dk] = exp(cum_i) * Q[i][dk]
        int i = tid >> 2, dc = (tid & 3) * 32;
        float a = aex[i];
#pragma unroll
        for (int q8 = 0; q8 < 4; q8++) {
            u16x8 o;
#pragma unroll
            for (int e = 0; e < 8; e++)
                o[e] = f2bf(a * bf2f(Ql[swzidx(i, dc + q8 * 8 + e, 128)]));
            *(u16x8*)(aQB + ch * 8192 + i * 128 + dc + q8 * 8) = o;
        }
    }
    if (tid == 0) aCB[ch] = aex[63];
}

// ---- phase A2: blocked forward substitution  X = (I+M)^{-1} [BV | -BaK] ----
__global__ __launch_bounds__(256) void k_solve(const u16* __restrict__ ksb, const u16* __restrict__ vsb,
                                               const float2* __restrict__ gb2, const float* __restrict__ Mbuf,
                                               float* __restrict__ TvB, u16* __restrict__ WB) {
    __shared__ float Ml[64 * 64];
    __shared__ u16 Kl[64 * 128];
    __shared__ u16 Vl[64 * 128];
    __shared__ u16 bounce[64 * 136];
    __shared__ float cum[64], bet[64], aex[64], gl[64];
    int bid = blockIdx.x;
    int chunk = bid & 15, hv = (bid >> 4) & 31, b = bid >> 9;
    int hk = hv >> 1;
    size_t ch = bid;
    int tid = threadIdx.x, wid = tid >> 6, lane = tid & 63;
    const u16* kg = ksb + ((size_t)(b * NK + hk) * S_ + chunk * 64) * 128;
    const u16* vg = vsb + ((size_t)(b * NV + hv) * S_ + chunk * 64) * 128;
    const float* mg = Mbuf + ch * 4096;
    for (int c = wid; c < 48; c += 4) {
        if (c < 16) gl16((const char*)mg + c * 1024 + lane * 16, (char*)Ml + c * 1024 + lane * 16);
        else if (c < 32) gl16((const char*)kg + (c - 16) * 1024 + lane * 16, (char*)Kl + (c - 16) * 1024 + lane * 16);
        else gl16((const char*)vg + (c - 32) * 1024 + lane * 16, (char*)Vl + (c - 32) * 1024 + lane * 16);
    }
    if (tid < 64) {
        float2 gv = gb2[(size_t)(b * NV + hv) * S_ + chunk * 64 + tid];
        gl[tid] = gv.x; bet[tid] = gv.y;
    }
    __syncthreads();
    if (tid == 0) { float s = 0.f; for (int i = 0; i < 64; i++) { s += gl[i]; cum[i] = s; } }
    __syncthreads();
    if (tid < 64) aex[tid] = __expf(cum[tid]);
    __syncthreads();
    int c = tid;
    float X[64];
    if (c < 128) {
#pragma unroll
        for (int i = 0; i < 64; i++) X[i] = bet[i] * bf2f(Vl[i * 128 + c]);
    } else {
        int d = c - 128;
#pragma unroll
        for (int i = 0; i < 64; i++) X[i] = -bet[i] * aex[i] * bf2f(Kl[i * 128 + d]);
    }
#pragma unroll
    for (int IB = 0; IB < 8; ++IB) {
#pragma unroll
        for (int JB = 0; JB < IB; ++JB) {
#pragma unroll
            for (int ii = 0; ii < 8; ++ii) {
                const float* mr = &Ml[(IB * 8 + ii) * 64 + JB * 8];
                float4 a = *(const float4*)mr, bq = *(const float4*)(mr + 4);
                float x = X[IB * 8 + ii];
                x = fmaf(-a.x, X[JB * 8 + 0], x); x = fmaf(-a.y, X[JB * 8 + 1], x);
                x = fmaf(-a.z, X[JB * 8 + 2], x); x = fmaf(-a.w, X[JB * 8 + 3], x);
                x = fmaf(-bq.x, X[JB * 8 + 4], x); x = fmaf(-bq.y, X[JB * 8 + 5], x);
                x = fmaf(-bq.z, X[JB * 8 + 6], x); x = fmaf(-bq.w, X[JB * 8 + 7], x);
                X[IB * 8 + ii] = x;
            }
        }
#pragma unroll
        for (int ii = 1; ii < 8; ++ii) {
            float x = X[IB * 8 + ii];
#pragma unroll
            for (int jj = 0; jj < ii; ++jj)
                x = fmaf(-Ml[(IB * 8 + ii) * 64 + IB * 8 + jj], X[IB * 8 + jj], x);
            X[IB * 8 + ii] = x;
        }
    }
    if (c < 128) {
        float* o = TvB + ch * 8192 + (size_t)c * 64;
#pragma unroll
        for (int q4 = 0; q4 < 16; q4++) {
            float4 v4 = { X[q4 * 4], X[q4 * 4 + 1], X[q4 * 4 + 2], X[q4 * 4 + 3] };
            *(float4*)(o + q4 * 4) = v4;
        }
    } else {
        int d = c - 128;
#pragma unroll
        for (int i = 0; i < 64; i++) bounce[i * 136 + d] = f2bf(X[i]);
    }
    __syncthreads();
    {
        int i = tid >> 2, dc = (tid & 3) * 32;
#pragma unroll
        for (int q8 = 0; q8 < 4; q8++) {
            u16x8 o;
#pragma unroll
            for (int e = 0; e < 8; e++) o[e] = bounce[i * 136 + dc + q8 * 8 + e];
            *(u16x8*)(WB + ch * 8192 + i * 128 + dc + q8 * 8) = o;
        }
    }
}

// ---- phase B: sequential chunks, state in LDS (bf16 hi+lo), all-MFMA ----
__global__ __launch_bounds__(256) void k_chunk(const float* __restrict__ TvB, const u16* __restrict__ WB,
                                               const u16* __restrict__ aQB, const u16* __restrict__ MqB,
                                               const u16* __restrict__ KtB, const float* __restrict__ aCB,
                                               float* __restrict__ core) {
    __shared__ u16 S0h[64 * 128], S0l[64 * 128];
    __shared__ u16 DTh[64 * 64], DTl[64 * 64];
    __shared__ float Tvl[64 * 64];
    __shared__ u16 Wl[64 * 128], aQl[64 * 128];
    __shared__ u16 Mql[64 * 64];
    __shared__ u16 Ktl[128 * 64];
    int bid = blockIdx.x;
    int split = bid & 1, bh = bid >> 1;
    int tid = threadIdx.x, wid = tid >> 6, lane = tid & 63;
    int l15 = lane & 15, lg = lane >> 4;
    float4 z4 = {0.f, 0.f, 0.f, 0.f};
    for (int i = tid; i < 64 * 128 / 8; i += 256) {
        *(float4*)(S0h + i * 8) = z4;
        *(float4*)(S0l + i * 8) = z4;
    }
    for (int chunk = 0; chunk < 16; ++chunk) {
        size_t ch = (size_t)bh * 16 + chunk;
        const char* tvg = (const char*)(TvB + ch * 8192 + (size_t)split * 64 * 64);
        const char* wg = (const char*)(WB + ch * 8192);
        const char* qg = (const char*)(aQB + ch * 8192);
        const char* mg = (const char*)(MqB + ch * 4096);
        const char* kg = (const char*)(KtB + ch * 8192);
        for (int c = wid; c < 72; c += 4) {
            if (c < 16) {
                gl16(tvg + c * 1024 + lane * 16, (char*)Tvl + c * 1024 + lane * 16);
            } else if (c < 32) {
                int cc = c - 16; int row = cc * 4 + (lane >> 4); int g = lane & 15;
                gl16(wg + row * 256 + ((g ^ (row & 7)) << 4), (char*)Wl + cc * 1024 + lane * 16);
            } else if (c < 48) {
                int cc = c - 32; int row = cc * 4 + (lane >> 4); int g = lane & 15;
                gl16(qg + row * 256 + ((g ^ (row & 7)) << 4), (char*)aQl + cc * 1024 + lane * 16);
            } else if (c < 56) {
                int cc = c - 48; int row = cc * 8 + (lane >> 3); int g = lane & 7;
                gl16(mg + row * 128 + ((g ^ (row & 7)) << 4), (char*)Mql + cc * 1024 + lane * 16);
            } else {
                int cc = c - 56; int row = cc * 8 + (lane >> 3); int g = lane & 7;
                gl16(kg + row * 128 + ((g ^ (row & 7)) << 4), (char*)Ktl + cc * 1024 + lane * 16);
            }
        }
        float aC = aCB[ch];
        __syncthreads();
        f32x4 Dacc[4], Oacc[4] = {};
#pragma unroll
        for (int nt = 0; nt < 4; nt++)
#pragma unroll
            for (int r = 0; r < 4; r++)
                Dacc[nt][r] = Tvl[(wid * 16 + lg * 4 + r) * 64 + nt * 16 + l15];
#pragma unroll
        for (int kk = 0; kk < 4; kk++) {
            bf16x8 aH = fragld(S0h, wid * 16 + l15, kk * 32 + lg * 8, 128);
            bf16x8 aL = fragld(S0l, wid * 16 + l15, kk * 32 + lg * 8, 128);
#pragma unroll
            for (int nt = 0; nt < 4; nt++) {
                bf16x8 bW = fragld(Wl, nt * 16 + l15, kk * 32 + lg * 8, 128);
                Dacc[nt] = __builtin_amdgcn_mfma_f32_16x16x32_bf16(aH, bW,
                           __builtin_amdgcn_mfma_f32_16x16x32_bf16(aL, bW, Dacc[nt], 0, 0, 0), 0, 0, 0);
                bf16x8 bQ = fragld(aQl, nt * 16 + l15, kk * 32 + lg * 8, 128);
                Oacc[nt] = __builtin_amdgcn_mfma_f32_16x16x32_bf16(aH, bQ,
                           __builtin_amdgcn_mfma_f32_16x16x32_bf16(aL, bQ, Oacc[nt], 0, 0, 0), 0, 0, 0);
            }
        }
#pragma unroll
        for (int nt = 0; nt < 4; nt++)
#pragma unroll
            for (int r = 0; r < 4; r++) {
                int dv = wid * 16 + lg * 4 + r, t = nt * 16 + l15;
                float x = Dacc[nt][r];
                u16 h = f2bf(x);
                int idx = swzidx(dv, t, 64);
                DTh[idx] = h; DTl[idx] = f2bf(x - bf2f(h));
            }
#pragma unroll
        for (int kk2 = 0; kk2 < 2; kk2++) {
            bf16x8 aDh = fragld(DTh, wid * 16 + l15, kk2 * 32 + lg * 8, 64);
            bf16x8 aDl = fragld(DTl, wid * 16 + l15, kk2 * 32 + lg * 8, 64);
#pragma unroll
            for (int nt = 0; nt < 4; nt++) {
                bf16x8 bM = fragld(Mql, nt * 16 + l15, kk2 * 32 + lg * 8, 64);
                Oacc[nt] = __builtin_amdgcn_mfma_f32_16x16x32_bf16(aDh, bM,
                           __builtin_amdgcn_mfma_f32_16x16x32_bf16(aDl, bM, Oacc[nt], 0, 0, 0), 0, 0, 0);
            }
        }
#pragma unroll
        for (int nt = 0; nt < 4; nt++) {
            float4 o = { Oacc[nt][0], Oacc[nt][1], Oacc[nt][2], Oacc[nt][3] };
            size_t t = (size_t)chunk * 64 + nt * 16 + l15;
            *(float4*)(core + ((size_t)bh * S_ + t) * 128 + split * 64 + wid * 16 + lg * 4) = o;
        }
        f32x4 Sacc[8] = {};
#pragma unroll
        for (int kk2 = 0; kk2 < 2; kk2++) {
            bf16x8 aDh = fragld(DTh, wid * 16 + l15, kk2 * 32 + lg * 8, 64);
            bf16x8 aDl = fragld(DTl, wid * 16 + l15, kk2 * 32 + lg * 8, 64);
#pragma unroll
            for (int nd = 0; nd < 8; nd++) {
                bf16x8 bK = fragld(Ktl, nd * 16 + l15, kk2 * 32 + lg * 8, 64);
                Sacc[nd] = __builtin_amdgcn_mfma_f32_16x16x32_bf16(aDh, bK,
                           __builtin_amdgcn_mfma_f32_16x16x32_bf16(aDl, bK, Sacc[nd], 0, 0, 0), 0, 0, 0);
            }
        }
#pragma unroll
        for (int nd = 0; nd < 8; nd++)
#pragma unroll
            for (int r = 0; r < 4; r++) {
                int dv = wid * 16 + lg * 4 + r, dk = nd * 16 + l15;
                int idx = swzidx(dv, dk, 128);
                float old = bf2f(S0h[idx]) + bf2f(S0l[idx]);
                float nu = fmaf(aC, old, Sacc[nd][r]);
                u16 h = f2bf(nu);
                S0h[idx] = h; S0l[idx] = f2bf(nu - bf2f(h));
            }
        __syncthreads();
    }
}

// ---------------- RMS-norm * norm_weight * silu(z) -> bf16 ----------------
__global__ __launch_bounds__(256) void k_gate(const float* __restrict__ core, const u16* __restrict__ qkvz,
                                              const float* __restrict__ nw, u16* __restrict__ gated) {
    int token = blockIdx.x, tid = threadIdx.x;
    int b = token >> 10, t = token & (S_ - 1);
    int grp = tid >> 3, l8 = tid & 7;
    const float* cp = core + ((size_t)(b * NV + grp) * S_ + t) * DV_ + l8 * 16;
    float vals[16];
    float ss = 0.f;
#pragma unroll
    for (int i = 0; i < 16; i++) { vals[i] = cp[i]; ss += vals[i] * vals[i]; }
    ss += __shfl_xor(ss, 1); ss += __shfl_xor(ss, 2); ss += __shfl_xor(ss, 4);
    float rms = rsqrtf(ss * (1.0f / DV_) + 1e-6f);
    const u16* zp = qkvz + (size_t)token * QKVZ_N + (grp >> 1) * 768 + 512 + (grp & 1) * 128 + l8 * 16;
    u16* op = gated + ((size_t)token * NV + grp) * DV_ + l8 * 16;
#pragma unroll
    for (int i = 0; i < 16; i++) {
        float z = bf2f(zp[i]);
        float sz = z / (1.f + __expf(-z));
        op[i] = f2bf(vals[i] * rms * nw[l8 * 16 + i] * sz);
    }
}

extern "C" void kernel_launch(void* const* d_in, const int* in_sizes, int n_in,
                              void* d_out, int out_size, void* d_ws, size_t ws_size,
                              hipStream_t stream) {
    const float* hidden = (const float*)d_in[0];
    const float* Wqkvz = (const float*)d_in[1];
    const float* Wba = (const float*)d_in[2];
    const float* convw = (const float*)d_in[3];
    const float* A_log = (const float*)d_in[4];
    const float* dt_bias = (const float*)d_in[5];
    const float* norm_w = (const float*)d_in[6];
    const float* Wout = (const float*)d_in[7];

    char* ws = (char*)d_ws;
    size_t off = 0;
    auto alloc = [&](size_t bytes) -> void* {
        void* p = ws + off;
        off += (bytes + 255) & ~(size_t)255;
        return p;
    };
    u16* hiddenB = (u16*)alloc((size_t)TOK * HID * 2);
    u16* WqT = (u16*)alloc((size_t)QKVZ_N * HID * 2);
    u16* WoT = (u16*)alloc((size_t)HID * 4096 * 2);
    u16* qkvz = (u16*)alloc((size_t)TOK * QKVZ_N * 2);
    float* ba = (float*)alloc((size_t)TOK * 64 * 4);
    u16* qsb = (u16*)alloc((size_t)B_ * NK * S_ * 128 * 2);
    u16* ksb = (u16*)alloc((size_t)B_ * NK * S_ * 128 * 2);
    u16* vsb = (u16*)alloc((size_t)B_ * NV * S_ * 128 * 2);
    float2* gb2 = (float2*)alloc((size_t)B_ * NV * S_ * 8);
    float* Mbuf = (float*)alloc((size_t)1024 * 4096 * 4);
    u16* MqB = (u16*)alloc((size_t)1024 * 4096 * 2);
    u16* KtB = (u16*)alloc((size_t)1024 * 8192 * 2);
    u16* aQB = (u16*)alloc((size_t)1024 * 8192 * 2);
    float* TvB = (float*)alloc((size_t)1024 * 8192 * 4);
    u16* WB = (u16*)alloc((size_t)1024 * 8192 * 2);
    float* aCB = (float*)alloc((size_t)1024 * 4);
    float* core = (float*)alloc((size_t)B_ * NV * S_ * 128 * 4);
    u16* gated = (u16*)alloc((size_t)TOK * 4096 * 2);

    k_cvt_bf16<<<4096, 256, 0, stream>>>(hidden, hiddenB, TOK * HID);
    k_transpose<<<dim3(QKVZ_N / 32, HID / 32), dim3(32, 8), 0, stream>>>(Wqkvz, WqT, HID, QKVZ_N);
    k_transpose<<<dim3(HID / 32, 4096 / 32), dim3(32, 8), 0, stream>>>(Wout, WoT, 4096, HID);
    k_gemm256<<<768, 512, 0, stream>>>(hiddenB, WqT, qkvz, HID, QKVZ_N);
    k_ba<<<TOK, 64, 0, stream>>>(hidden, Wba, ba);
    k_conv<<<TOK, 256, 0, stream>>>(qkvz, ba, convw, A_log, dt_bias, qsb, ksb, vsb, gb2);
    k_prep<<<1024, 256, 0, stream>>>(ksb, qsb, gb2, Mbuf, MqB, KtB, aQB, aCB);
    k_solve<<<1024, 256, 0, stream>>>(ksb, vsb, gb2, Mbuf, TvB, WB);
    k_chunk<<<128, 256, 0, stream>>>(TvB, WB, aQB, MqB, KtB, aCB, core);
    k_gate<<<TOK, 256, 0, stream>>>(core, qkvz, norm_w, gated);
    k_gemm<0><<<dim3(HID / 128, TOK / 128), 256, 0, stream>>>(gated, WoT, d_out, 4096, HID);
}